// Round 1
// baseline (174.087 us; speedup 1.0000x reference)
//
#include <hip/hip_runtime.h>

#define HP 192
#define WP 192
#define NPIX (HP * WP)   // 36864
#define CDIM 64
#define NHEADS 4
#define HDIM 16
#define KS 7
#define SG 24

// ---------------- Kernel 1: QKV projection -----------------------------------
// grid (144, 6), block 256. Each thread: one pixel, one 32-column chunk of the
// concatenated [64 x 192] weight (cols 0..63 q, 64..127 k, 128..191 v).
// Weight loads are lane-uniform -> compiler scalarizes to s_load (SGPR operand FMA).
__global__ __launch_bounds__(256) void qkv_kernel(
    const float* __restrict__ x,
    const float* __restrict__ w_qk,
    const float* __restrict__ w_v,
    float* __restrict__ qb, float* __restrict__ kb, float* __restrict__ vb) {
  const int jb = blockIdx.y;  // 0..5
  const int pix = blockIdx.x * 256 + threadIdx.x;
  float xv[64];
#pragma unroll
  for (int c = 0; c < 64; ++c) xv[c] = x[c * NPIX + pix];
  float acc[32];
#pragma unroll
  for (int j = 0; j < 32; ++j) acc[j] = 0.f;
  const int j0 = jb * 32;
  if (jb < 4) {
#pragma unroll
    for (int c = 0; c < 64; ++c) {
      const float* wr = w_qk + c * 128 + j0;
      const float xc = xv[c];
#pragma unroll
      for (int j = 0; j < 32; ++j) acc[j] = fmaf(xc, wr[j], acc[j]);
    }
  } else {
#pragma unroll
    for (int c = 0; c < 64; ++c) {
      const float* wr = w_v + c * 64 + (j0 - 128);
      const float xc = xv[c];
#pragma unroll
      for (int j = 0; j < 32; ++j) acc[j] = fmaf(xc, wr[j], acc[j]);
    }
  }
  float* dst;
  float mul = 1.0f;
  if (jb < 2) {
    dst = qb + (size_t)pix * 64 + j0;
    mul = 0.25f;  // hd^-0.5, hd=16
  } else if (jb < 4) {
    dst = kb + (size_t)pix * 64 + (j0 - 64);
  } else {
    dst = vb + (size_t)pix * 64 + (j0 - 128);
  }
#pragma unroll
  for (int j = 0; j < 32; ++j) dst[j] = acc[j] * mul;
}

// ---------------- Kernel 2: neighborhood attention + superpixel reweight -----
// One block per 8x8 pixel tile (24x24 tiles). 256 threads = 64 pixels x 4 heads.
// Tile-aligned trick: all pixels in the tile share sh0 = tileRow, sw0 = tileCol,
// so the 9 candidate superpixel labels are block-uniform. Stage
// pi[loc = 14x14 spatial][s = 9 labels] in LDS (padded stride 12 for float4).
__global__ __launch_bounds__(256) void attn_kernel(
    const float* __restrict__ qb, const float* __restrict__ kb,
    const float* __restrict__ vb, const float* __restrict__ sims,
    float* __restrict__ pre) {
  __shared__ __align__(16) float smpi[196 * 12];
  const int tile = blockIdx.x;
  const int th = tile / 24, tw = tile % 24;
  const int rowBase = th * 8 - 3, colBase = tw * 8 - 3;
  const int tid = threadIdx.x;

  // stage pi table: 196 spatial locs x 9 labels
  for (int i = tid; i < 196 * 9; i += 256) {
    const int loc = i / 9, s = i - loc * 9;
    const int rl = loc / 14, cl = loc - rl * 14;
    const int r = rowBase + rl, c = colBase + cl;
    const int dh = s / 3, dw = s - dh * 3;
    const int shi = th + dh - 1, swj = tw + dw - 1;
    float val = 0.f;
    if (shi >= 0 && shi < SG && swj >= 0 && swj < SG && r >= 0 && r < HP &&
        c >= 0 && c < WP)
      val = sims[((size_t)(r * WP + c)) * (SG * SG) + shi * SG + swj];
    smpi[loc * 12 + s] = val;
  }
  __syncthreads();

  const int head = tid & 3;
  const int pl = tid >> 2;
  const int py = pl >> 3, px = pl & 7;
  const int h = th * 8 + py, w = tw * 8 + px;
  const int pix = h * WP + w;
  int hs = h - 3;
  hs = hs < 0 ? 0 : (hs > HP - KS ? HP - KS : hs);
  int wsb = w - 3;
  wsb = wsb < 0 ? 0 : (wsb > WP - KS ? WP - KS : wsb);

  const float4* qp = (const float4*)(qb + (size_t)pix * 64 + head * 16);
  const float4 q0 = qp[0], q1 = qp[1], q2 = qp[2], q3 = qp[3];

  // ---- logits ----
  float a[49];
#pragma unroll
  for (int kh = 0; kh < 7; ++kh) {
    const int hn = hs + kh;
#pragma unroll
    for (int kw = 0; kw < 7; ++kw) {
      const int wn = wsb + kw;
      const float4* kp =
          (const float4*)(kb + (size_t)(hn * WP + wn) * 64 + head * 16);
      const float4 k0 = kp[0], k1 = kp[1], k2 = kp[2], k3 = kp[3];
      float t = q0.x * k0.x + q0.y * k0.y + q0.z * k0.z + q0.w * k0.w;
      t += q1.x * k1.x + q1.y * k1.y + q1.z * k1.z + q1.w * k1.w;
      t += q2.x * k2.x + q2.y * k2.y + q2.z * k2.z + q2.w * k2.w;
      t += q3.x * k3.x + q3.y * k3.y + q3.z * k3.z + q3.w * k3.w;
      a[kh * 7 + kw] = t;
    }
  }
  // ---- softmax over 49 ----
  float m = a[0];
#pragma unroll
  for (int i = 1; i < 49; ++i) m = fmaxf(m, a[i]);
  float ssum = 0.f;
#pragma unroll
  for (int i = 0; i < 49; ++i) {
    a[i] = __expf(a[i] - m);
    ssum += a[i];
  }
  const float inv = 1.0f / ssum;
#pragma unroll
  for (int i = 0; i < 49; ++i) a[i] *= inv;

  // ---- pass 1: d_s = sum_kk a[kk] * pi[s,kk] ----
  float d9[9];
#pragma unroll
  for (int s = 0; s < 9; ++s) d9[s] = 0.f;
#pragma unroll
  for (int kh = 0; kh < 7; ++kh) {
    const int rl = hs + kh - rowBase;
#pragma unroll
    for (int kw = 0; kw < 7; ++kw) {
      const int cl = wsb + kw - colBase;
      const float* pp = smpi + (rl * 14 + cl) * 12;
      const float4 p0 = *(const float4*)pp;
      const float4 p1 = *(const float4*)(pp + 4);
      const float p8 = pp[8];
      const float akk = a[kh * 7 + kw];
      d9[0] = fmaf(akk, p0.x, d9[0]);
      d9[1] = fmaf(akk, p0.y, d9[1]);
      d9[2] = fmaf(akk, p0.z, d9[2]);
      d9[3] = fmaf(akk, p0.w, d9[3]);
      d9[4] = fmaf(akk, p1.x, d9[4]);
      d9[5] = fmaf(akk, p1.y, d9[5]);
      d9[6] = fmaf(akk, p1.z, d9[6]);
      d9[7] = fmaf(akk, p1.w, d9[7]);
      d9[8] = fmaf(akk, p8, d9[8]);
    }
  }
  // ---- coef_s = w_s[s] / (d_s + 1e-10) ----
  float coef[9];
  {
    const int rl = h - rowBase, cl = w - colBase;  // pixel's own location
    const float* pp = smpi + (rl * 14 + cl) * 12;
    const float4 p0 = *(const float4*)pp;
    const float4 p1 = *(const float4*)(pp + 4);
    const float p8 = pp[8];
    coef[0] = p0.x / (d9[0] + 1e-10f);
    coef[1] = p0.y / (d9[1] + 1e-10f);
    coef[2] = p0.z / (d9[2] + 1e-10f);
    coef[3] = p0.w / (d9[3] + 1e-10f);
    coef[4] = p1.x / (d9[4] + 1e-10f);
    coef[5] = p1.y / (d9[5] + 1e-10f);
    coef[6] = p1.z / (d9[6] + 1e-10f);
    coef[7] = p1.w / (d9[7] + 1e-10f);
    coef[8] = p8 / (d9[8] + 1e-10f);
  }
  // ---- pass 2: attn2[kk] = a[kk] * sum_s coef_s*pi[s,kk]; aggregate v ----
  float4 o0 = make_float4(0.f, 0.f, 0.f, 0.f);
  float4 o1 = make_float4(0.f, 0.f, 0.f, 0.f);
  float4 o2 = make_float4(0.f, 0.f, 0.f, 0.f);
  float4 o3 = make_float4(0.f, 0.f, 0.f, 0.f);
#pragma unroll
  for (int kh = 0; kh < 7; ++kh) {
    const int hn = hs + kh;
    const int rl = hn - rowBase;
#pragma unroll
    for (int kw = 0; kw < 7; ++kw) {
      const int wn = wsb + kw;
      const int cl = wn - colBase;
      const float* pp = smpi + (rl * 14 + cl) * 12;
      const float4 p0 = *(const float4*)pp;
      const float4 p1 = *(const float4*)(pp + 4);
      const float p8 = pp[8];
      float t = coef[0] * p0.x + coef[1] * p0.y + coef[2] * p0.z +
                coef[3] * p0.w + coef[4] * p1.x + coef[5] * p1.y +
                coef[6] * p1.z + coef[7] * p1.w + coef[8] * p8;
      const float a2 = a[kh * 7 + kw] * t;
      const float4* vp =
          (const float4*)(vb + (size_t)(hn * WP + wn) * 64 + head * 16);
      const float4 v0 = vp[0], v1 = vp[1], v2 = vp[2], v3 = vp[3];
      o0.x = fmaf(a2, v0.x, o0.x);
      o0.y = fmaf(a2, v0.y, o0.y);
      o0.z = fmaf(a2, v0.z, o0.z);
      o0.w = fmaf(a2, v0.w, o0.w);
      o1.x = fmaf(a2, v1.x, o1.x);
      o1.y = fmaf(a2, v1.y, o1.y);
      o1.z = fmaf(a2, v1.z, o1.z);
      o1.w = fmaf(a2, v1.w, o1.w);
      o2.x = fmaf(a2, v2.x, o2.x);
      o2.y = fmaf(a2, v2.y, o2.y);
      o2.z = fmaf(a2, v2.z, o2.z);
      o2.w = fmaf(a2, v2.w, o2.w);
      o3.x = fmaf(a2, v3.x, o3.x);
      o3.y = fmaf(a2, v3.y, o3.y);
      o3.z = fmaf(a2, v3.z, o3.z);
      o3.w = fmaf(a2, v3.w, o3.w);
    }
  }
  float4* op = (float4*)(pre + (size_t)pix * 64 + head * 16);
  op[0] = o0;
  op[1] = o1;
  op[2] = o2;
  op[3] = o3;
}

// ---------------- Kernel 3: output projection --------------------------------
// grid (144, 2), block 256. Thread: one pixel, 32 output channels.
__global__ __launch_bounds__(256) void proj_kernel(
    const float* __restrict__ pre, const float* __restrict__ w_proj,
    float* __restrict__ out) {
  const int jb = blockIdx.y;  // 0..1
  const int pix = blockIdx.x * 256 + threadIdx.x;
  float xv[64];
  const float4* pp = (const float4*)(pre + (size_t)pix * 64);
#pragma unroll
  for (int i = 0; i < 16; ++i) {
    const float4 t = pp[i];
    xv[i * 4 + 0] = t.x;
    xv[i * 4 + 1] = t.y;
    xv[i * 4 + 2] = t.z;
    xv[i * 4 + 3] = t.w;
  }
  float acc[32];
#pragma unroll
  for (int j = 0; j < 32; ++j) acc[j] = 0.f;
  const int j0 = jb * 32;
#pragma unroll
  for (int c = 0; c < 64; ++c) {
    const float* wr = w_proj + c * 64 + j0;
    const float xc = xv[c];
#pragma unroll
    for (int j = 0; j < 32; ++j) acc[j] = fmaf(xc, wr[j], acc[j]);
  }
#pragma unroll
  for (int j = 0; j < 32; ++j) out[(size_t)(j0 + j) * NPIX + pix] = acc[j];
}

extern "C" void kernel_launch(void* const* d_in, const int* in_sizes, int n_in,
                              void* d_out, int out_size, void* d_ws,
                              size_t ws_size, hipStream_t stream) {
  const float* x = (const float*)d_in[0];
  const float* sims = (const float*)d_in[1];
  const float* w_qk = (const float*)d_in[2];
  const float* w_v = (const float*)d_in[3];
  const float* w_proj = (const float*)d_in[4];
  float* out = (float*)d_out;

  float* qb = (float*)d_ws;
  float* kb = qb + (size_t)NPIX * 64;
  float* vb = kb + (size_t)NPIX * 64;
  float* pre = vb + (size_t)NPIX * 64;

  qkv_kernel<<<dim3(144, 6), 256, 0, stream>>>(x, w_qk, w_v, qb, kb, vb);
  attn_kernel<<<dim3(576), 256, 0, stream>>>(qb, kb, vb, sims, pre);
  proj_kernel<<<dim3(144, 2), 256, 0, stream>>>(pre, w_proj, out);
}